// Round 5
// baseline (199.352 us; speedup 1.0000x reference)
//
#include <hip/hip_runtime.h>
#include <stdint.h>

#define BB 4
#define CC 256
#define NN 4096
#define GG 8

typedef unsigned short u16;
typedef __attribute__((ext_vector_type(4))) float f32x4;
typedef __attribute__((ext_vector_type(16))) float f32x16;
typedef __attribute__((ext_vector_type(8))) short s16x8;
typedef __attribute__((ext_vector_type(4))) u16 u16x4;
typedef __attribute__((ext_vector_type(8))) u16 u16x8;

__device__ __forceinline__ u16 f2bf(float f) {
  union { float f; uint32_t u; } v; v.f = f;
  return (u16)((v.u + 0x7FFFu + ((v.u >> 16) & 1u)) >> 16);
}
__device__ __forceinline__ float bf2f(uint32_t u) {
  union { uint32_t u; float f; } v; v.u = u << 16;
  return v.f;
}

__device__ __forceinline__ void async16(const void* g, void* l) {
  __builtin_amdgcn_global_load_lds(
      (const __attribute__((address_space(1))) void*)g,
      (__attribute__((address_space(3))) void*)l, 16, 0, 0);
}

// ---------------- weight f32 -> bf16 ----------------
__global__ __launch_bounds__(256) void wcvt_kernel(
    const float* __restrict__ w0, const float* __restrict__ w1,
    const float* __restrict__ w2, const float* __restrict__ w3,
    u16* __restrict__ dst) {
  const float* src = (blockIdx.y == 0) ? w0 : (blockIdx.y == 1) ? w1
                   : (blockIdx.y == 2) ? w2 : w3;
  int i = blockIdx.x * 256 + threadIdx.x;
  f32x4 v = ((const f32x4*)src)[i];
  u16x4 o;
  o[0] = f2bf(v[0]); o[1] = f2bf(v[1]); o[2] = f2bf(v[2]); o[3] = f2bf(v[3]);
  ((u16x4*)(dst + (size_t)blockIdx.y * 65536))[i] = o;
}

// ---------------- GroupNorm partial sums: 256 blocks ----------------
__global__ __launch_bounds__(256) void gn_part_kernel(
    const float* __restrict__ x, float* __restrict__ part) {
  int bg = blockIdx.x, seg = blockIdx.y;  // 32 x 8
  const f32x4* xp = (const f32x4*)(x + (size_t)bg * 131072 + seg * 16384);
  float s = 0.f, ss = 0.f;
  for (int i = threadIdx.x; i < 4096; i += 256) {
    f32x4 v = xp[i];
    s += v[0] + v[1] + v[2] + v[3];
    ss += v[0]*v[0] + v[1]*v[1] + v[2]*v[2] + v[3]*v[3];
  }
  for (int d = 1; d < 64; d <<= 1) {
    s += __shfl_xor(s, d, 64);
    ss += __shfl_xor(ss, d, 64);
  }
  __shared__ float red[8];
  int w = threadIdx.x >> 6, lane = threadIdx.x & 63;
  if (lane == 0) { red[w*2] = s; red[w*2+1] = ss; }
  __syncthreads();
  if (threadIdx.x == 0) {
    part[(bg*8 + seg)*2]     = red[0]+red[2]+red[4]+red[6];
    part[(bg*8 + seg)*2 + 1] = red[1]+red[3]+red[5]+red[7];
  }
}

// ======== fused GN-apply + QKV GEMM ========
__global__ __launch_bounds__(512) void gnqkv_kernel(
    const float* __restrict__ x, const float* __restrict__ part,
    const float* __restrict__ gamma, const float* __restrict__ beta,
    const u16* __restrict__ wbf,
    const float* __restrict__ bq, const float* __restrict__ bk,
    const float* __restrict__ bv,
    u16* __restrict__ Qtm, u16* __restrict__ Ktm, u16* __restrict__ Vcm) {
  __shared__ float gstat[16];
  __shared__ char t1[32768];  // [256 c][64 n] bf16, XOR-swizzled
  __shared__ char t2[32768];  // [64 n][256 c] bf16, row-swizzled for B-frags
  const int b = blockIdx.y, n0 = blockIdx.x * 64, t = threadIdx.x;
  if (t < 8) {
    float S = 0.f, SS = 0.f;
    for (int seg = 0; seg < 8; ++seg) {
      S  += part[((b*8 + t)*8 + seg)*2];
      SS += part[((b*8 + t)*8 + seg)*2 + 1];
    }
    float mean = S * (1.0f/131072.0f);
    float var = SS * (1.0f/131072.0f) - mean*mean;
    gstat[t*2] = mean;
    gstat[t*2+1] = rsqrtf(var + 1e-5f);
  }
  __syncthreads();
  for (int p = 0; p < 8; ++p) {
    int c = p*32 + (t >> 4);
    int n4 = (t & 15) * 4;
    f32x4 v = *(const f32x4*)(x + ((size_t)b*CC + c)*NN + n0 + n4);
    float mean = gstat[(c>>5)*2], rstd = gstat[(c>>5)*2+1];
    float ga = gamma[c] * rstd;
    float be = beta[c] - mean * ga;
    u16x4 o;
    o[0]=f2bf(v[0]*ga+be); o[1]=f2bf(v[1]*ga+be);
    o[2]=f2bf(v[2]*ga+be); o[3]=f2bf(v[3]*ga+be);
    int swz = (((c & 7) ^ ((c >> 3) & 7)) << 4);
    *(u16x4*)(t1 + c*128 + ((n4*2) ^ swz)) = o;
  }
  __syncthreads();
  for (int p = 0; p < 4; ++p) {
    int n = p*16 + (t >> 5);
    int c0 = (t & 31) * 8;
    u16x8 o;
#pragma unroll
    for (int j = 0; j < 8; ++j) {
      int c = c0 + j;
      int swz = (((c & 7) ^ ((c >> 3) & 7)) << 4);
      o[j] = *(const u16*)(t1 + c*128 + ((n*2) ^ swz));
    }
    *(u16x8*)(t2 + n*512 + ((c0*2) ^ ((n & 7) << 4))) = o;
  }
  __syncthreads();
  const int lane = t & 63, w = t >> 6;
  const int wn = w >> 2, wo = w & 3;
  const int hi = lane >> 4, lo = lane & 15;
#pragma unroll
  for (int mat = 0; mat < 3; ++mat) {
    const u16* wm = wbf + mat*65536;
    f32x4 acc[2][4] = {};
    for (int kc = 0; kc < 8; ++kc) {
      s16x8 xf[2];
#pragma unroll
      for (int nf = 0; nf < 2; ++nf) {
        int n = wn*32 + nf*16 + lo;
        xf[nf] = *(const s16x8*)(t2 + n*512 + ((kc*64 + hi*16) ^ ((n & 7) << 4)));
      }
#pragma unroll
      for (int of = 0; of < 4; ++of) {
        int o = wo*64 + of*16 + lo;
        s16x8 wf = *(const s16x8*)(wm + (size_t)o*256 + kc*32 + hi*8);
        if (mat < 2) {
          acc[0][of] = __builtin_amdgcn_mfma_f32_16x16x32_bf16(xf[0], wf, acc[0][of], 0, 0, 0);
          acc[1][of] = __builtin_amdgcn_mfma_f32_16x16x32_bf16(xf[1], wf, acc[1][of], 0, 0, 0);
        } else {
          acc[0][of] = __builtin_amdgcn_mfma_f32_16x16x32_bf16(wf, xf[0], acc[0][of], 0, 0, 0);
          acc[1][of] = __builtin_amdgcn_mfma_f32_16x16x32_bf16(wf, xf[1], acc[1][of], 0, 0, 0);
        }
      }
    }
    if (mat < 2) {
      u16* Y = (mat == 0) ? Qtm : Ktm;
      const float* bias = (mat == 0) ? bq : bk;
#pragma unroll
      for (int nf = 0; nf < 2; ++nf)
#pragma unroll
        for (int of = 0; of < 4; ++of) {
          int oc = wo*64 + of*16 + lo;
          float bvv = bias[oc];
#pragma unroll
          for (int r = 0; r < 4; ++r) {
            int n = n0 + wn*32 + nf*16 + hi*4 + r;
            Y[((size_t)b*NN + n)*CC + oc] = f2bf(acc[nf][of][r] + bvv);
          }
        }
    } else {
#pragma unroll
      for (int nf = 0; nf < 2; ++nf)
#pragma unroll
        for (int of = 0; of < 4; ++of)
#pragma unroll
          for (int r = 0; r < 4; ++r) {
            int oc = wo*64 + of*16 + hi*4 + r;
            int n = n0 + wn*32 + nf*16 + lo;
            Vcm[((size_t)b*CC + oc)*NN + n] = f2bf(acc[nf][of][r] + bv[oc]);
          }
    }
  }
}

// ======== flash v5: producer/consumer wave specialization ========
// Block: 256 thr = 4 waves; per q-subtile (32 q) one S-wave + one PV-wave.
// S-wave: S(t) = K(t)·Q^T (32m x 32q), softmax, P(t)->LDS (bf16 B-frags).
// PV-wave: O^T += V(t-1)^T · P(t-1). K staged 2 ahead, V 1 ahead (counted vmcnt).
// Block covers 64 q, m in [part*2048, +2048), 64 m-tiles of 32.
__global__ __launch_bounds__(256, 2) void flash_kernel(
    const u16* __restrict__ Q, const u16* __restrict__ K,
    const u16* __restrict__ V, uint32_t* __restrict__ Op32,
    float* __restrict__ Lpart) {
  extern __shared__ char smem[];
  char* kl = smem;            // 2 x 16KB: addr = cslot*512 + m*16
  char* vl = smem + 32768;    // 2 x 16KB: addr = mslot*4096 + c*16
  char* pl = smem + 65536;    // 2 x 4KB:  [qsub][ks][h][q][16B]
  const int bid = blockIdx.x;
  const int b    = bid & 3;
  const int part = (bid >> 2) & 1;
  const int qb   = bid >> 3;            // 0..63
  const int tid = threadIdx.x;
  const int lane = tid & 63;
  const int w = tid >> 6;
  const int qsub = w >> 1;
  const int role = (w ^ (bid >> 3)) & 1;  // 0 = S-wave, 1 = PV-wave (mixed per SIMD)
  const int cl = lane & 31;
  const int h  = lane >> 5;
  const int q = qb*64 + qsub*32 + cl;

  s16x8 qreg[16];
  if (role == 0) {
    const u16* qp = Q + ((size_t)b*NN + q)*CC + h*8;
#pragma unroll
    for (int kc = 0; kc < 16; ++kc) qreg[kc] = *(const s16x8*)(qp + kc*16);
  }
  f32x16 oacc[8];
#pragma unroll
  for (int i = 0; i < 8; ++i) oacc[i] = (f32x16)0.f;
  float Lp = 0.f;

  const char* kbase = (const char*)(K + (size_t)b*NN*CC) + (size_t)part*2048*512;
  const char* vbase = (const char*)(V + (size_t)b*CC*NN) + (size_t)part*2048*2;

  auto stageK = [&](int j) {   // m-tile j -> kl[j&1]
    char* dst = kl + (j & 1)*16384 + tid*16;
    const char* src = kbase + (size_t)(j*32 + (tid & 31))*512 + (tid >> 5)*16;
#pragma unroll
    for (int p = 0; p < 4; ++p)
      async16(src + p*128, dst + p*4096);
  };
  auto stageV = [&](int j) {   // m-tile j -> vl[j&1]
    char* dst = vl + (j & 1)*16384 + tid*16;
    const char* src = vbase + (size_t)tid*8192 + j*64;
#pragma unroll
    for (int p = 0; p < 4; ++p)
      async16(src + p*16, dst + p*4096);
  };

  stageK(0); stageK(1); stageV(0);

  const float SC = 0.0901684857f;  // log2(e)/16

  for (int t = 0; t <= 64; ++t) {
    if (t <= 62)      asm volatile("s_waitcnt vmcnt(8)" ::: "memory");
    else if (t == 63) asm volatile("s_waitcnt vmcnt(4)" ::: "memory");
    else              asm volatile("s_waitcnt vmcnt(0)" ::: "memory");
    __builtin_amdgcn_s_barrier();
    asm volatile("" ::: "memory");

    if (role == 0) {
      if (t < 64) {
        const char* kc_base = kl + (t & 1)*16384;
        f32x16 s0 = (f32x16)0.f;
        __builtin_amdgcn_s_setprio(1);
#pragma unroll
        for (int kc = 0; kc < 16; ++kc) {
          s16x8 kf = *(const s16x8*)(kc_base + (kc*2 + h)*512 + cl*16);
          s0 = __builtin_amdgcn_mfma_f32_32x32x16_bf16(kf, qreg[kc], s0, 0, 0, 0);
        }
        __builtin_amdgcn_s_setprio(0);
        char* pw = pl + (t & 1)*4096 + qsub*2048 + h*512 + cl*16;
#pragma unroll
        for (int half = 0; half < 2; ++half) {
          float pe[8];
#pragma unroll
          for (int j = 0; j < 8; ++j) {
            float xs = s0[half*8 + j] * SC;
            float p;
            asm("v_exp_f32 %0, %1" : "=v"(p) : "v"(xs));
            pe[j] = p;
            Lp += p;
          }
          uint32_t a0, a1, a2, a3;
          asm("v_cvt_pk_bf16_f32 %0, %1, %2" : "=v"(a0) : "v"(pe[0]), "v"(pe[1]));
          asm("v_cvt_pk_bf16_f32 %0, %1, %2" : "=v"(a1) : "v"(pe[2]), "v"(pe[3]));
          asm("v_cvt_pk_bf16_f32 %0, %1, %2" : "=v"(a2) : "v"(pe[4]), "v"(pe[5]));
          asm("v_cvt_pk_bf16_f32 %0, %1, %2" : "=v"(a3) : "v"(pe[6]), "v"(pe[7]));
          asm("v_permlane32_swap_b32 %0, %1" : "+v"(a0), "+v"(a2));
          asm("v_permlane32_swap_b32 %0, %1" : "+v"(a1), "+v"(a3));
          union { uint32_t wd[4]; s16x8 v; } u;
          u.wd[0] = a0; u.wd[1] = a1; u.wd[2] = a2; u.wd[3] = a3;
          *(s16x8*)(pw + half*1024) = u.v;
        }
      }
    } else {
      if (t > 0) {
        const int pv = (t - 1) & 1;
        const char* vc_base = vl + pv*16384;
        const char* pr = pl + pv*4096 + qsub*2048 + h*512 + cl*16;
        s16x8 pf0 = *(const s16x8*)(pr);
        s16x8 pf1 = *(const s16x8*)(pr + 1024);
        __builtin_amdgcn_s_setprio(1);
#pragma unroll
        for (int ct = 0; ct < 8; ++ct) {
          s16x8 vf = *(const s16x8*)(vc_base + h*4096 + (ct*32 + cl)*16);
          oacc[ct] = __builtin_amdgcn_mfma_f32_32x32x16_bf16(vf, pf0, oacc[ct], 0, 0, 0);
        }
#pragma unroll
        for (int ct = 0; ct < 8; ++ct) {
          s16x8 vf = *(const s16x8*)(vc_base + (2 + h)*4096 + (ct*32 + cl)*16);
          oacc[ct] = __builtin_amdgcn_mfma_f32_32x32x16_bf16(vf, pf1, oacc[ct], 0, 0, 0);
        }
        __builtin_amdgcn_s_setprio(0);
      }
    }
    asm volatile("s_waitcnt lgkmcnt(0)" ::: "memory");
    __builtin_amdgcn_s_barrier();
    if (t <= 61) stageK(t + 2);
    if (t <= 62) stageV(t + 1);
  }

  const int pb = part*4 + b;
  if (role == 0) {
    float Lq = Lp + __shfl_xor(Lp, 32, 64);
    if (lane < 32) Lpart[(size_t)pb*NN + q] = Lq;
  } else {
    const size_t basePB = (size_t)pb * 128 * NN;
#pragma unroll
    for (int ct = 0; ct < 8; ++ct) {
#pragma unroll
      for (int i2 = 0; i2 < 8; ++i2) {
        const int i = i2*2;
        float lo_ = oacc[ct][i], hi_ = oacc[ct][i+1];
        uint32_t pk;
        asm("v_cvt_pk_bf16_f32 %0, %1, %2" : "=v"(pk) : "v"(lo_), "v"(hi_));
        const int cp = ct*16 + ((i&3)>>1) + 4*(i>>2) + 2*h;  // c/2
        Op32[basePB + (size_t)cp*NN + q] = pk;
      }
    }
  }
}

// ======== fused merge(2 partials) + proj GEMM + bias + fp32 residual ========
__global__ __launch_bounds__(512) void proj_kernel(
    const uint32_t* __restrict__ Op32, const float* __restrict__ Lpart,
    const u16* __restrict__ wp, const float* __restrict__ bp,
    const float* __restrict__ resid, float* __restrict__ out) {
  __shared__ char t2[32768];  // [64 m][256 c] bf16, row-swizzled
  const int b = blockIdx.y, m0 = blockIdx.x * 64, t = threadIdx.x;
  {
    const int q = m0 + (t & 63);
    const int m = t & 63;
    const int cg = t >> 6;  // 0..7
    float L = 0.f;
#pragma unroll
    for (int p = 0; p < 2; ++p) L += Lpart[(size_t)(p*4 + b)*NN + q];
    const float inv = 1.0f / L;
#pragma unroll
    for (int i = 0; i < 16; ++i) {
      const int cp = cg*16 + i;
      float v0 = 0.f, v1 = 0.f;
#pragma unroll
      for (int p = 0; p < 2; ++p) {
        uint32_t pk = Op32[(size_t)(p*4 + b)*128*NN + (size_t)cp*NN + q];
        v0 += bf2f(pk & 0xffffu);
        v1 += bf2f(pk >> 16);
      }
      v0 *= inv; v1 *= inv;
      uint32_t opk;
      asm("v_cvt_pk_bf16_f32 %0, %1, %2" : "=v"(opk) : "v"(v0), "v"(v1));
      *(uint32_t*)(t2 + m*512 + ((cp*4) ^ ((m & 7) << 4))) = opk;
    }
  }
  __syncthreads();
  const int lane = t & 63, w = t >> 6;
  const int wm = w >> 2, wo = w & 3;
  const int hi = lane >> 4, lo = lane & 15;
  f32x4 acc[2][4] = {};
  for (int kc = 0; kc < 8; ++kc) {
    s16x8 xf[2];
#pragma unroll
    for (int mf = 0; mf < 2; ++mf) {
      int m = wm*32 + mf*16 + lo;
      xf[mf] = *(const s16x8*)(t2 + m*512 + ((kc*64 + hi*16) ^ ((m & 7) << 4)));
    }
#pragma unroll
    for (int of = 0; of < 4; ++of) {
      int o = wo*64 + of*16 + lo;
      s16x8 wf = *(const s16x8*)(wp + (size_t)o*256 + kc*32 + hi*8);
      acc[0][of] = __builtin_amdgcn_mfma_f32_16x16x32_bf16(wf, xf[0], acc[0][of], 0, 0, 0);
      acc[1][of] = __builtin_amdgcn_mfma_f32_16x16x32_bf16(wf, xf[1], acc[1][of], 0, 0, 0);
    }
  }
#pragma unroll
  for (int mf = 0; mf < 2; ++mf)
#pragma unroll
    for (int of = 0; of < 4; ++of) {
      int oc0 = wo*64 + of*16 + hi*4;
#pragma unroll
      for (int r = 0; r < 4; ++r) {
        int m = m0 + wm*32 + mf*16 + lo;
        size_t idx = ((size_t)b*CC + oc0 + r)*NN + m;
        out[idx] = acc[mf][of][r] + bp[oc0 + r] + resid[idx];
      }
    }
}

extern "C" void kernel_launch(void* const* d_in, const int* in_sizes, int n_in,
                              void* d_out, int out_size, void* d_ws, size_t ws_size,
                              hipStream_t stream) {
  const float* x  = (const float*)d_in[0];
  const float* gg = (const float*)d_in[1];
  const float* gb = (const float*)d_in[2];
  const float* wq = (const float*)d_in[3];
  const float* bq = (const float*)d_in[4];
  const float* wk = (const float*)d_in[5];
  const float* bk = (const float*)d_in[6];
  const float* wv = (const float*)d_in[7];
  const float* bv = (const float*)d_in[8];
  const float* wp = (const float*)d_in[9];
  const float* bp = (const float*)d_in[10];
  float* out = (float*)d_out;

  char* ws = (char*)d_ws;
  const size_t MATS = (size_t)BB * NN * CC;
  u16* wbf  = (u16*)ws;                 // 512 KB (Q,K,V,P bf16 weights)
  u16* Qtm  = (u16*)(ws + (512 << 10)); // 8 MB token-major
  u16* Ktm  = Qtm + MATS;               // 8 MB token-major
  u16* Vcm  = Ktm + MATS;               // 8 MB channel-major
  uint32_t* Op32 = (uint32_t*)(Vcm + MATS);            // 8*128*4096*4 = 16.8 MB
  float* Lpart   = (float*)(Op32 + (size_t)8*128*NN);  // 128 KB
  float* part    = Lpart + (size_t)8*NN;               // 512 floats

  wcvt_kernel<<<dim3(64, 4), 256, 0, stream>>>(wq, wk, wv, wp, wbf);
  gn_part_kernel<<<dim3(32, 8), 256, 0, stream>>>(x, part);
  gnqkv_kernel<<<dim3(64, 4), 512, 0, stream>>>(x, part, gg, gb, wbf,
                                                bq, bk, bv, Qtm, Ktm, Vcm);
  hipFuncSetAttribute((const void*)flash_kernel,
                      hipFuncAttributeMaxDynamicSharedMemorySize, 73728);
  flash_kernel<<<512, 256, 73728, stream>>>(Qtm, Ktm, Vcm, Op32, Lpart);
  proj_kernel<<<dim3(64, 4), 512, 0, stream>>>(Op32, Lpart, wp ? wbf + 3*65536 : wbf,
                                               bp, x, out);
}